// Round 1
// baseline (1008.259 us; speedup 1.0000x reference)
//
#include <hip/hip_runtime.h>
#include <cstdint>
#include <cstddef>

typedef __bf16 bf16x8 __attribute__((ext_vector_type(8)));
typedef float f32x4 __attribute__((ext_vector_type(4)));
typedef unsigned short u16;

namespace {
constexpr int Bb = 4, Tt = 2048, Cc = 1024, Hh = 16, Dd = 64;
constexpr int ROWS = Bb * Tt;   // 8192
constexpr int C3 = 3 * Cc;      // 3072
constexpr float LNEPS = 1e-5f;
}

__device__ __forceinline__ u16 f2bf(float f) {
  union { float f; unsigned u; } v; v.f = f;
  return (u16)((v.u + 0x7fffu + ((v.u >> 16) & 1u)) >> 16);
}

// ---------------- LayerNorm (fp32 in -> bf16 out) ----------------
__global__ __launch_bounds__(256) void ln_kernel(
    const float* __restrict__ x, const float* __restrict__ g,
    const float* __restrict__ b, u16* __restrict__ out)
{
  const int row = blockIdx.x;
  const int tid = threadIdx.x;
  const float4 v = reinterpret_cast<const float4*>(x + (size_t)row * Cc)[tid];
  float s  = v.x + v.y + v.z + v.w;
  float ss = v.x * v.x + v.y * v.y + v.z * v.z + v.w * v.w;
#pragma unroll
  for (int off = 32; off; off >>= 1) {
    s  += __shfl_xor(s, off);
    ss += __shfl_xor(ss, off);
  }
  __shared__ float sa[4], sb[4];
  const int w = tid >> 6;
  if ((tid & 63) == 0) { sa[w] = s; sb[w] = ss; }
  __syncthreads();
  s  = sa[0] + sa[1] + sa[2] + sa[3];
  ss = sb[0] + sb[1] + sb[2] + sb[3];
  const float mu   = s * (1.0f / Cc);
  const float var  = ss * (1.0f / Cc) - mu * mu;
  const float rstd = rsqrtf(var + LNEPS);
  const float4 gv = reinterpret_cast<const float4*>(g)[tid];
  const float4 bv = reinterpret_cast<const float4*>(b)[tid];
  ushort4 o;
  o.x = f2bf((v.x - mu) * rstd * gv.x + bv.x);
  o.y = f2bf((v.y - mu) * rstd * gv.y + bv.y);
  o.z = f2bf((v.z - mu) * rstd * gv.z + bv.z);
  o.w = f2bf((v.w - mu) * rstd * gv.w + bv.w);
  reinterpret_cast<ushort4*>(out + (size_t)row * Cc)[tid] = o;
}

// ---------------- weight transpose + cast: w[K][N] f32 -> wt[N][K] bf16 ----------------
__global__ __launch_bounds__(256) void wcast_t(
    const float* __restrict__ w, u16* __restrict__ wt, int K, int N)
{
  __shared__ float tile[32][33];
  const int n0 = blockIdx.x * 32, k0 = blockIdx.y * 32;
  const int tx = threadIdx.x & 31, ty = threadIdx.x >> 5; // 32x8
#pragma unroll
  for (int i = 0; i < 4; i++)
    tile[ty + i * 8][tx] = w[(size_t)(k0 + ty + i * 8) * N + n0 + tx];
  __syncthreads();
#pragma unroll
  for (int i = 0; i < 4; i++)
    wt[(size_t)(n0 + ty + i * 8) * K + k0 + tx] = f2bf(tile[tx][ty + i * 8]);
}

// ---------------- GEMM: C[M][N] = A[M][K] * Bt[N][K]^T, fused epilogues ----------------
enum { EPI_BIAS_BF16 = 0, EPI_BIAS_RELU_BF16 = 1, EPI_BIAS_RES_F32 = 2 };

template <int EPI>
__global__ __launch_bounds__(256, 2) void gemm_bt(
    const u16* __restrict__ A, const u16* __restrict__ Bt,
    const float* __restrict__ bias, const float* __restrict__ res,
    void* __restrict__ outp, int M, int N, int K)
{
  constexpr int BM = 128, BN = 128, BK = 64;
  __shared__ alignas(16) u16 As[BM][BK];
  __shared__ alignas(16) u16 Bs[BN][BK];
  const int tid  = threadIdx.x;
  const int lane = tid & 63;
  const int wv   = tid >> 6;
  const int wr   = wv >> 1, wc = wv & 1;
  const int lr   = lane & 15, lg = lane >> 4;
  const int bm = blockIdx.x * BM;
  const int bn = blockIdx.y * BN;

  f32x4 acc[4][4];
#pragma unroll
  for (int mi = 0; mi < 4; mi++)
#pragma unroll
    for (int nj = 0; nj < 4; nj++)
      acc[mi][nj] = (f32x4){0.f, 0.f, 0.f, 0.f};

  const int srow = tid >> 3;          // 0..31
  const int scol = (tid & 7) * 8;     // 0,8,..,56

  for (int k0 = 0; k0 < K; k0 += BK) {
#pragma unroll
    for (int p = 0; p < 4; p++) {
      const int r = srow + p * 32;
      bf16x8 va = *reinterpret_cast<const bf16x8*>(&A [(size_t)(bm + r) * K + k0 + scol]);
      bf16x8 vb = *reinterpret_cast<const bf16x8*>(&Bt[(size_t)(bn + r) * K + k0 + scol]);
      *reinterpret_cast<bf16x8*>(&As[r][scol]) = va;
      *reinterpret_cast<bf16x8*>(&Bs[r][scol]) = vb;
    }
    __syncthreads();
#pragma unroll
    for (int kk = 0; kk < BK; kk += 32) {
      bf16x8 af[4], bfr[4];
#pragma unroll
      for (int mi = 0; mi < 4; mi++)
        af[mi] = *reinterpret_cast<const bf16x8*>(&As[wr * 64 + mi * 16 + lr][kk + lg * 8]);
#pragma unroll
      for (int nj = 0; nj < 4; nj++)
        bfr[nj] = *reinterpret_cast<const bf16x8*>(&Bs[wc * 64 + nj * 16 + lr][kk + lg * 8]);
#pragma unroll
      for (int mi = 0; mi < 4; mi++)
#pragma unroll
        for (int nj = 0; nj < 4; nj++)
          acc[mi][nj] = __builtin_amdgcn_mfma_f32_16x16x32_bf16(af[mi], bfr[nj], acc[mi][nj], 0, 0, 0);
    }
    __syncthreads();
  }

#pragma unroll
  for (int mi = 0; mi < 4; mi++) {
#pragma unroll
    for (int nj = 0; nj < 4; nj++) {
      const int col = bn + wc * 64 + nj * 16 + lr;
      const float bv = bias[col];
#pragma unroll
      for (int r = 0; r < 4; r++) {
        const int row = bm + wr * 64 + mi * 16 + lg * 4 + r;
        float v = acc[mi][nj][r] + bv;
        if constexpr (EPI == EPI_BIAS_RELU_BF16) v = fmaxf(v, 0.0f);
        if constexpr (EPI == EPI_BIAS_RES_F32) {
          float* out = (float*)outp;
          out[(size_t)row * N + col] = v + res[(size_t)row * N + col];
        } else {
          ((u16*)outp)[(size_t)row * N + col] = f2bf(v);
        }
      }
    }
  }
}

// ---------------- V transpose: qkv[B][T][3C] (v part) -> vt[B][H][D][T] ----------------
__global__ __launch_bounds__(256) void build_vt(
    const u16* __restrict__ qkv, u16* __restrict__ vt)
{
  __shared__ u16 tile[64][80]; // [t][d], pitch 80 (160B: 16B-aligned rows, bank-spread)
  const int t0 = blockIdx.x * 64;
  const int h  = blockIdx.y;
  const int b  = blockIdx.z;
  const int tid = threadIdx.x;
  const int rr = tid >> 3, cc = (tid & 7) * 8;
#pragma unroll
  for (int p = 0; p < 2; p++) {
    const int t = rr + p * 32;
    bf16x8 v = *reinterpret_cast<const bf16x8*>(
        &qkv[(size_t)(b * Tt + t0 + t) * C3 + 2 * Cc + h * Dd + cc]);
    *reinterpret_cast<bf16x8*>(&tile[t][cc]) = v;
  }
  __syncthreads();
#pragma unroll
  for (int p = 0; p < 2; p++) {
    const int d = rr + p * 32;
    const int tc = cc;
    union { u16 u[8]; int4 v; } o;
#pragma unroll
    for (int j = 0; j < 8; j++) o.u[j] = tile[tc + j][d];
    *reinterpret_cast<int4*>(&vt[(size_t)((b * Hh + h) * Dd + d) * Tt + t0 + tc]) = o.v;
  }
}

// ---------------- flash attention: causal, scale 1/8 ----------------
__global__ __launch_bounds__(256) void flash_attn(
    const u16* __restrict__ qkv,   // [B][T][3C]
    const u16* __restrict__ vt,    // [B][H][D][T]
    u16* __restrict__ y)           // [B][T][C]
{
  __shared__ alignas(16) u16 pbuf[4][16][40];
  const int tid = threadIdx.x, lane = tid & 63, wv = tid >> 6;
  const int h = blockIdx.y, b = blockIdx.z;
  const int q0 = blockIdx.x * 64 + wv * 16;
  const int lr = lane & 15, lg = lane >> 4;

  bf16x8 qf[2];
#pragma unroll
  for (int kk = 0; kk < 2; kk++)
    qf[kk] = *reinterpret_cast<const bf16x8*>(
        &qkv[(size_t)(b * Tt + q0 + lr) * C3 + h * Dd + kk * 32 + lg * 8]);

  f32x4 yacc[4];
#pragma unroll
  for (int nj = 0; nj < 4; nj++) yacc[nj] = (f32x4){0.f, 0.f, 0.f, 0.f};
  float mrun[4], lrun[4];
#pragma unroll
  for (int r = 0; r < 4; r++) { mrun[r] = -INFINITY; lrun[r] = 0.0f; }

  const int kmax = q0 + 15;
  for (int k0 = 0; k0 <= kmax; k0 += 32) {
    f32x4 s[2];
    s[0] = (f32x4){0.f, 0.f, 0.f, 0.f};
    s[1] = (f32x4){0.f, 0.f, 0.f, 0.f};
#pragma unroll
    for (int nt = 0; nt < 2; nt++) {
#pragma unroll
      for (int kk = 0; kk < 2; kk++) {
        bf16x8 kf = *reinterpret_cast<const bf16x8*>(
            &qkv[(size_t)(b * Tt + k0 + nt * 16 + lr) * C3 + Cc + h * Dd + kk * 32 + lg * 8]);
        s[nt] = __builtin_amdgcn_mfma_f32_16x16x32_bf16(qf[kk], kf, s[nt], 0, 0, 0);
      }
    }
    float sv[2][4];
    const bool need_mask = (k0 + 31 > q0);
#pragma unroll
    for (int nt = 0; nt < 2; nt++)
#pragma unroll
      for (int r = 0; r < 4; r++) {
        float xv = s[nt][r] * 0.125f;
        if (need_mask && (k0 + nt * 16 + lr > q0 + lg * 4 + r)) xv = -INFINITY;
        sv[nt][r] = xv;
      }
#pragma unroll
    for (int r = 0; r < 4; r++) {
      float mx = fmaxf(sv[0][r], sv[1][r]);
#pragma unroll
      for (int off = 1; off < 16; off <<= 1) mx = fmaxf(mx, __shfl_xor(mx, off));
      const float mnew  = fmaxf(mrun[r], mx);
      const float alpha = __expf(mrun[r] - mnew);
      mrun[r] = mnew;
      const float p0 = __expf(sv[0][r] - mnew);
      const float p1 = __expf(sv[1][r] - mnew);
      sv[0][r] = p0; sv[1][r] = p1;
      float ps = p0 + p1;
#pragma unroll
      for (int off = 1; off < 16; off <<= 1) ps += __shfl_xor(ps, off);
      lrun[r] = lrun[r] * alpha + ps;
#pragma unroll
      for (int nj = 0; nj < 4; nj++) yacc[nj][r] *= alpha;
    }
#pragma unroll
    for (int nt = 0; nt < 2; nt++)
#pragma unroll
      for (int r = 0; r < 4; r++)
        pbuf[wv][lg * 4 + r][nt * 16 + lr] = f2bf(sv[nt][r]);
    bf16x8 pa = *reinterpret_cast<const bf16x8*>(&pbuf[wv][lr][lg * 8]);
#pragma unroll
    for (int nj = 0; nj < 4; nj++) {
      bf16x8 vf = *reinterpret_cast<const bf16x8*>(
          &vt[(size_t)((b * Hh + h) * Dd + nj * 16 + lr) * Tt + k0 + lg * 8]);
      yacc[nj] = __builtin_amdgcn_mfma_f32_16x16x32_bf16(pa, vf, yacc[nj], 0, 0, 0);
    }
  }
#pragma unroll
  for (int nj = 0; nj < 4; nj++)
#pragma unroll
    for (int r = 0; r < 4; r++) {
      const int row = q0 + lg * 4 + r;
      const float v = yacc[nj][r] / lrun[r];
      y[(size_t)(b * Tt + row) * Cc + h * Dd + nj * 16 + lr] = f2bf(v);
    }
}

// ---------------- launch ----------------
extern "C" void kernel_launch(void* const* d_in, const int* in_sizes, int n_in,
                              void* d_out, int out_size, void* d_ws, size_t ws_size,
                              hipStream_t stream)
{
  const float* x      = (const float*)d_in[0];
  const float* ln1_g  = (const float*)d_in[1];
  const float* ln1_b  = (const float*)d_in[2];
  const float* attn_w = (const float*)d_in[3];
  const float* attn_b = (const float*)d_in[4];
  const float* proj_w = (const float*)d_in[5];
  const float* proj_b = (const float*)d_in[6];
  const float* ln2_g  = (const float*)d_in[7];
  const float* ln2_b  = (const float*)d_in[8];
  const float* fc1_w  = (const float*)d_in[9];
  const float* fc1_b  = (const float*)d_in[10];
  const float* fc2_w  = (const float*)d_in[11];
  const float* fc2_b  = (const float*)d_in[12];
  float* out = (float*)d_out;

  char* ws = (char*)d_ws;
  size_t o = 0;
  auto alloc = [&](size_t bytes) { char* p = ws + o; o += bytes; return p; };
  u16* wqkv_t  = (u16*)alloc((size_t)C3 * Cc * 2);        // 6.29 MB
  u16* wproj_t = (u16*)alloc((size_t)Cc * Cc * 2);        // 2.10 MB
  u16* wfc1_t  = (u16*)alloc((size_t)4096 * Cc * 2);      // 8.39 MB
  u16* wfc2_t  = (u16*)alloc((size_t)Cc * 4096 * 2);      // 8.39 MB
  u16* h_bf    = (u16*)alloc((size_t)ROWS * Cc * 2);      // 16.8 MB
  u16* y_bf    = (u16*)alloc((size_t)ROWS * Cc * 2);      // 16.8 MB
  u16* qkv_raw = (u16*)alloc((size_t)ROWS * C3 * 2);      // 50.3 MB
  u16* vt      = (u16*)alloc((size_t)Bb * Hh * Dd * Tt * 2); // 16.8 MB (adjacent to qkv_raw)
  u16* hh      = qkv_raw; // aliases qkv_raw+vt (67.1 MB), both dead by FC1 time

  // weights -> bf16 transposed
  wcast_t<<<dim3(C3 / 32, Cc / 32), 256, 0, stream>>>(attn_w, wqkv_t, Cc, C3);
  wcast_t<<<dim3(Cc / 32, Cc / 32), 256, 0, stream>>>(proj_w, wproj_t, Cc, Cc);
  wcast_t<<<dim3(4096 / 32, Cc / 32), 256, 0, stream>>>(fc1_w, wfc1_t, Cc, 4096);
  wcast_t<<<dim3(Cc / 32, 4096 / 32), 256, 0, stream>>>(fc2_w, wfc2_t, 4096, Cc);

  // ln1(x) -> h_bf
  ln_kernel<<<ROWS, 256, 0, stream>>>(x, ln1_g, ln1_b, h_bf);
  // qkv = h @ attn_w + attn_b
  gemm_bt<EPI_BIAS_BF16><<<dim3(ROWS / 128, C3 / 128), 256, 0, stream>>>(
      h_bf, wqkv_t, attn_b, nullptr, qkv_raw, ROWS, C3, Cc);
  // v transpose
  build_vt<<<dim3(Tt / 64, Hh, Bb), 256, 0, stream>>>(qkv_raw, vt);
  // attention -> y_bf
  flash_attn<<<dim3(Tt / 64, Hh, Bb), 256, 0, stream>>>(qkv_raw, vt, y_bf);
  // out = x + y @ proj_w + proj_b    (fp32)
  gemm_bt<EPI_BIAS_RES_F32><<<dim3(ROWS / 128, Cc / 128), 256, 0, stream>>>(
      y_bf, wproj_t, proj_b, x, out, ROWS, Cc, Cc);
  // ln2(out) -> h_bf
  ln_kernel<<<ROWS, 256, 0, stream>>>(out, ln2_g, ln2_b, h_bf);
  // hh = relu(h @ fc1_w + fc1_b)
  gemm_bt<EPI_BIAS_RELU_BF16><<<dim3(ROWS / 128, 4096 / 128), 256, 0, stream>>>(
      h_bf, wfc1_t, fc1_b, nullptr, hh, ROWS, 4096, Cc);
  // out = out + hh @ fc2_w + fc2_b
  gemm_bt<EPI_BIAS_RES_F32><<<dim3(ROWS / 128, Cc / 128), 256, 0, stream>>>(
      hh, wfc2_t, fc2_b, out, out, ROWS, Cc, 4096);
}

// Round 2
// 550.325 us; speedup vs baseline: 1.8321x; 1.8321x over previous
//
#include <hip/hip_runtime.h>
#include <cstdint>
#include <cstddef>

typedef __bf16 bf16x8 __attribute__((ext_vector_type(8)));
typedef float f32x4 __attribute__((ext_vector_type(4)));
typedef unsigned short u16;

namespace {
constexpr int Bb = 4, Tt = 2048, Cc = 1024, Hh = 16, Dd = 64;
constexpr int ROWS = Bb * Tt;   // 8192
constexpr int C3 = 3 * Cc;      // 3072
constexpr float LNEPS = 1e-5f;
constexpr float SCL2 = 0.18033688011112042f; // 0.125 * log2(e)
}

__device__ __forceinline__ u16 f2bf(float f) {
  union { float f; unsigned u; } v; v.f = f;
  return (u16)((v.u + 0x7fffu + ((v.u >> 16) & 1u)) >> 16);
}

typedef __attribute__((address_space(3))) unsigned lds_u32;
typedef __attribute__((address_space(1))) const unsigned glb_u32;
__device__ __forceinline__ void gload_lds16(const u16* g, u16* l) {
  __builtin_amdgcn_global_load_lds((glb_u32*)g, (lds_u32*)l, 16, 0, 0);
}

// ---------------- LayerNorm (fp32 in -> bf16 out) ----------------
__global__ __launch_bounds__(256) void ln_kernel(
    const float* __restrict__ x, const float* __restrict__ g,
    const float* __restrict__ b, u16* __restrict__ out)
{
  const int row = blockIdx.x;
  const int tid = threadIdx.x;
  const float4 v = reinterpret_cast<const float4*>(x + (size_t)row * Cc)[tid];
  float s  = v.x + v.y + v.z + v.w;
  float ss = v.x * v.x + v.y * v.y + v.z * v.z + v.w * v.w;
#pragma unroll
  for (int off = 32; off; off >>= 1) {
    s  += __shfl_xor(s, off);
    ss += __shfl_xor(ss, off);
  }
  __shared__ float sa[4], sb[4];
  const int w = tid >> 6;
  if ((tid & 63) == 0) { sa[w] = s; sb[w] = ss; }
  __syncthreads();
  s  = sa[0] + sa[1] + sa[2] + sa[3];
  ss = sb[0] + sb[1] + sb[2] + sb[3];
  const float mu   = s * (1.0f / Cc);
  const float var  = ss * (1.0f / Cc) - mu * mu;
  const float rstd = rsqrtf(var + LNEPS);
  const float4 gv = reinterpret_cast<const float4*>(g)[tid];
  const float4 bv = reinterpret_cast<const float4*>(b)[tid];
  ushort4 o;
  o.x = f2bf((v.x - mu) * rstd * gv.x + bv.x);
  o.y = f2bf((v.y - mu) * rstd * gv.y + bv.y);
  o.z = f2bf((v.z - mu) * rstd * gv.z + bv.z);
  o.w = f2bf((v.w - mu) * rstd * gv.w + bv.w);
  reinterpret_cast<ushort4*>(out + (size_t)row * Cc)[tid] = o;
}

// ---------------- weight transpose + cast: w[K][N] f32 -> wt[N][K] bf16 ----------------
__global__ __launch_bounds__(256) void wcast_t(
    const float* __restrict__ w, u16* __restrict__ wt, int K, int N)
{
  __shared__ float tile[32][33];
  const int n0 = blockIdx.x * 32, k0 = blockIdx.y * 32;
  const int tx = threadIdx.x & 31, ty = threadIdx.x >> 5; // 32x8
#pragma unroll
  for (int i = 0; i < 4; i++)
    tile[ty + i * 8][tx] = w[(size_t)(k0 + ty + i * 8) * N + n0 + tx];
  __syncthreads();
#pragma unroll
  for (int i = 0; i < 4; i++)
    wt[(size_t)(n0 + ty + i * 8) * K + k0 + tx] = f2bf(tile[tx][ty + i * 8]);
}

// ---------------- GEMM: C[M][N] = A[M][K] * Bt[N][K]^T, fused epilogues ----------------
// m97 structure: 128x128x64 tile, global_load_lds width=16 staging, 4 waves.
enum { EPI_BIAS_BF16 = 0, EPI_BIAS_RELU_BF16 = 1, EPI_BIAS_RES_F32 = 2 };

template <int EPI>
__global__ __launch_bounds__(256, 3) void gemm_bt(
    const u16* __restrict__ A, const u16* __restrict__ Bt,
    const float* __restrict__ bias, const float* __restrict__ res,
    void* __restrict__ outp, int M, int N, int K)
{
  constexpr int BM = 128, BN = 128, BK = 64;
  __shared__ alignas(16) u16 As[BM][BK];
  __shared__ alignas(16) u16 Bs[BN][BK];
  const int tid  = threadIdx.x;
  const int lane = tid & 63;
  const int wv   = tid >> 6;
  const int wr   = wv >> 1, wc = wv & 1;
  const int lr   = lane & 15, lg = lane >> 4;
  const int bm = blockIdx.x * BM;
  const int bn = blockIdx.y * BN;

  f32x4 acc[4][4];
#pragma unroll
  for (int mi = 0; mi < 4; mi++)
#pragma unroll
    for (int nj = 0; nj < 4; nj++)
      acc[mi][nj] = (f32x4){0.f, 0.f, 0.f, 0.f};

  // staging geometry: lane covers row (tid>>3), 16B chunk (tid&7)
  const int srow = tid >> 3;          // 0..31
  const int scol = (tid & 7) * 8;     // 0,8,..,56 (elems)
  const u16* ga = &A [(size_t)(bm + srow) * K + scol];
  const u16* gb = &Bt[(size_t)(bn + srow) * K + scol];
  u16* as_dst = &As[0][0] + (size_t)tid * 8;   // wave base + lane*16B
  u16* bs_dst = &Bs[0][0] + (size_t)tid * 8;

  for (int k0 = 0; k0 < K; k0 += BK) {
#pragma unroll
    for (int p = 0; p < 4; p++) {
      gload_lds16(ga + (size_t)p * 32 * K + k0, as_dst + p * 2048);
      gload_lds16(gb + (size_t)p * 32 * K + k0, bs_dst + p * 2048);
    }
    __syncthreads();
#pragma unroll
    for (int kk = 0; kk < BK; kk += 32) {
      bf16x8 af[4], bfr[4];
#pragma unroll
      for (int mi = 0; mi < 4; mi++)
        af[mi] = *reinterpret_cast<const bf16x8*>(&As[wr * 64 + mi * 16 + lr][kk + lg * 8]);
#pragma unroll
      for (int nj = 0; nj < 4; nj++)
        bfr[nj] = *reinterpret_cast<const bf16x8*>(&Bs[wc * 64 + nj * 16 + lr][kk + lg * 8]);
#pragma unroll
      for (int mi = 0; mi < 4; mi++)
#pragma unroll
        for (int nj = 0; nj < 4; nj++)
          acc[mi][nj] = __builtin_amdgcn_mfma_f32_16x16x32_bf16(af[mi], bfr[nj], acc[mi][nj], 0, 0, 0);
    }
    __syncthreads();
  }

#pragma unroll
  for (int mi = 0; mi < 4; mi++) {
#pragma unroll
    for (int nj = 0; nj < 4; nj++) {
      const int col = bn + wc * 64 + nj * 16 + lr;
      const float bv = bias[col];
#pragma unroll
      for (int r = 0; r < 4; r++) {
        const int row = bm + wr * 64 + mi * 16 + lg * 4 + r;
        float v = acc[mi][nj][r] + bv;
        if constexpr (EPI == EPI_BIAS_RELU_BF16) v = fmaxf(v, 0.0f);
        if constexpr (EPI == EPI_BIAS_RES_F32) {
          float* out = (float*)outp;
          out[(size_t)row * N + col] = v + res[(size_t)row * N + col];
        } else {
          ((u16*)outp)[(size_t)row * N + col] = f2bf(v);
        }
      }
    }
  }
}

// ---------------- V transpose: qkv[B][T][3C] (v part) -> vt[B][H][D][T] ----------------
__global__ __launch_bounds__(256) void build_vt(
    const u16* __restrict__ qkv, u16* __restrict__ vt)
{
  __shared__ u16 tile[64][80];
  const int t0 = blockIdx.x * 64;
  const int h  = blockIdx.y;
  const int b  = blockIdx.z;
  const int tid = threadIdx.x;
  const int rr = tid >> 3, cc = (tid & 7) * 8;
#pragma unroll
  for (int p = 0; p < 2; p++) {
    const int t = rr + p * 32;
    bf16x8 v = *reinterpret_cast<const bf16x8*>(
        &qkv[(size_t)(b * Tt + t0 + t) * C3 + 2 * Cc + h * Dd + cc]);
    *reinterpret_cast<bf16x8*>(&tile[t][cc]) = v;
  }
  __syncthreads();
#pragma unroll
  for (int p = 0; p < 2; p++) {
    const int d = rr + p * 32;
    union { u16 u[8]; int4 v; } o;
#pragma unroll
    for (int j = 0; j < 8; j++) o.u[j] = tile[cc + j][d];
    *reinterpret_cast<int4*>(&vt[(size_t)((b * Hh + h) * Dd + d) * Tt + t0 + cc]) = o.v;
  }
}

// ---------------- flash attention: causal, swapped-QK^T in-lane softmax ----------------
// Each wave owns 16 q-rows (lane's q = q0 + (lane&15)); block does q-tiles
// {bx, 31-bx} for uniform causal work. Swapped mfma(K,Q) puts a q-row's
// scores lane-local: max = 8 in-lane + 2 shfl; sum deferred to a per-lane
// partial reduced once at the end. Skip-rescale when __all(max<=mrun).
__global__ __launch_bounds__(256, 4) void flash_attn(
    const u16* __restrict__ qkv,   // [B][T][3C]
    const u16* __restrict__ vt,    // [B][H][D][T]
    u16* __restrict__ y)           // [B][T][C]
{
  __shared__ alignas(16) u16 pbuf[4][16][40];
  const int tid = threadIdx.x, lane = tid & 63, wv = tid >> 6;
  const int h = blockIdx.y, b = blockIdx.z;
  const int lr = lane & 15, lg = lane >> 4;
  const int lgq = lg * 4;            // base local q-row of this lane's acc rows
  const int bsel = lane & 48;        // keep shfl source within own lg group

  const int tiles[2] = { (int)blockIdx.x, (Tt / 64 - 1) - (int)blockIdx.x };

  for (int ti = 0; ti < 2; ti++) {
    const int q0 = tiles[ti] * 64 + wv * 16;
    const int qidx = q0 + lr;          // this lane's q-row

    bf16x8 qf[2];
#pragma unroll
    for (int kk = 0; kk < 2; kk++)
      qf[kk] = *reinterpret_cast<const bf16x8*>(
          &qkv[(size_t)(b * Tt + q0 + lr) * C3 + h * Dd + kk * 32 + lg * 8]);

    f32x4 yacc[4];
#pragma unroll
    for (int nj = 0; nj < 4; nj++) yacc[nj] = (f32x4){0.f, 0.f, 0.f, 0.f};
    float mrun = -INFINITY;
    float lpart = 0.0f;

    const int kmax = q0 + 15;
    const u16* kbase = &qkv[(size_t)(b * Tt) * C3 + Cc + h * Dd];
    const u16* vbase = &vt[(size_t)(b * Hh + h) * Dd * Tt];

    bf16x8 kf[2][2];
#pragma unroll
    for (int nt = 0; nt < 2; nt++)
#pragma unroll
      for (int kk = 0; kk < 2; kk++)
        kf[nt][kk] = *reinterpret_cast<const bf16x8*>(
            &kbase[(size_t)(nt * 16 + lr) * C3 + kk * 32 + lg * 8]);

    for (int k0 = 0; k0 <= kmax; k0 += 32) {
      // V loads for current tile (issued early; used after softmax)
      bf16x8 vf[4];
#pragma unroll
      for (int nj = 0; nj < 4; nj++)
        vf[nj] = *reinterpret_cast<const bf16x8*>(
            &vbase[(size_t)(nj * 16 + lr) * Tt + k0 + lg * 8]);

      // swapped QK^T: S^T[key][q], key = k0+nt*16+lg*4+r, q = q0+lr
      f32x4 s[2];
      s[0] = (f32x4){0.f, 0.f, 0.f, 0.f};
      s[1] = (f32x4){0.f, 0.f, 0.f, 0.f};
#pragma unroll
      for (int nt = 0; nt < 2; nt++)
#pragma unroll
        for (int kk = 0; kk < 2; kk++)
          s[nt] = __builtin_amdgcn_mfma_f32_16x16x32_bf16(kf[nt][kk], qf[kk], s[nt], 0, 0, 0);

      // prefetch next K tile
      const int k1 = k0 + 32;
      bf16x8 kn[2][2];
      if (k1 <= kmax) {
#pragma unroll
        for (int nt = 0; nt < 2; nt++)
#pragma unroll
          for (int kk = 0; kk < 2; kk++)
            kn[nt][kk] = *reinterpret_cast<const bf16x8*>(
                &kbase[(size_t)(k1 + nt * 16 + lr) * C3 + kk * 32 + lg * 8]);
      }

      // scale + causal mask, log2 domain
      float sv[2][4];
      const bool need_mask = (k0 + 31 > q0);
#pragma unroll
      for (int nt = 0; nt < 2; nt++)
#pragma unroll
        for (int r = 0; r < 4; r++) {
          float xv = s[nt][r] * SCL2;
          if (need_mask && (k0 + nt * 16 + lgq + r > qidx)) xv = -INFINITY;
          sv[nt][r] = xv;
        }

      // in-lane max of 8, then reduce over the 4 lanes sharing this q
      float m8 = fmaxf(fmaxf(fmaxf(sv[0][0], sv[0][1]), fmaxf(sv[0][2], sv[0][3])),
                       fmaxf(fmaxf(sv[1][0], sv[1][1]), fmaxf(sv[1][2], sv[1][3])));
      m8 = fmaxf(m8, __shfl_xor(m8, 16));
      m8 = fmaxf(m8, __shfl_xor(m8, 32));

      if (!__all(m8 <= mrun)) {
        const float mnew  = fmaxf(mrun, m8);
        const float alpha = exp2f(mrun - mnew);
        mrun = mnew;
        lpart *= alpha;
        float ar[4];
#pragma unroll
        for (int r = 0; r < 4; r++) ar[r] = __shfl(alpha, bsel | (lgq + r));
#pragma unroll
        for (int nj = 0; nj < 4; nj++)
#pragma unroll
          for (int r = 0; r < 4; r++) yacc[nj][r] *= ar[r];
      }

      float psum = 0.0f;
#pragma unroll
      for (int nt = 0; nt < 2; nt++)
#pragma unroll
        for (int r = 0; r < 4; r++) {
          const float p = exp2f(sv[nt][r] - mrun);
          psum += p;
          pbuf[wv][lr][nt * 16 + lgq + r] = f2bf(p);
        }
      lpart += psum;

      bf16x8 pa = *reinterpret_cast<const bf16x8*>(&pbuf[wv][lr][lg * 8]);
#pragma unroll
      for (int nj = 0; nj < 4; nj++)
        yacc[nj] = __builtin_amdgcn_mfma_f32_16x16x32_bf16(pa, vf[nj], yacc[nj], 0, 0, 0);

#pragma unroll
      for (int nt = 0; nt < 2; nt++)
#pragma unroll
        for (int kk = 0; kk < 2; kk++)
          kf[nt][kk] = kn[nt][kk];
    }

    // final row-sum reduce + normalize + store
    float ls = lpart + __shfl_xor(lpart, 16);
    ls += __shfl_xor(ls, 32);
    const float inv = 1.0f / ls;
    float invr[4];
#pragma unroll
    for (int r = 0; r < 4; r++) invr[r] = __shfl(inv, bsel | (lgq + r));
#pragma unroll
    for (int nj = 0; nj < 4; nj++)
#pragma unroll
      for (int r = 0; r < 4; r++)
        y[(size_t)(b * Tt + q0 + lgq + r) * Cc + h * Dd + nj * 16 + lr] =
            f2bf(yacc[nj][r] * invr[r]);
  }
}

// ---------------- launch ----------------
extern "C" void kernel_launch(void* const* d_in, const int* in_sizes, int n_in,
                              void* d_out, int out_size, void* d_ws, size_t ws_size,
                              hipStream_t stream)
{
  const float* x      = (const float*)d_in[0];
  const float* ln1_g  = (const float*)d_in[1];
  const float* ln1_b  = (const float*)d_in[2];
  const float* attn_w = (const float*)d_in[3];
  const float* attn_b = (const float*)d_in[4];
  const float* proj_w = (const float*)d_in[5];
  const float* proj_b = (const float*)d_in[6];
  const float* ln2_g  = (const float*)d_in[7];
  const float* ln2_b  = (const float*)d_in[8];
  const float* fc1_w  = (const float*)d_in[9];
  const float* fc1_b  = (const float*)d_in[10];
  const float* fc2_w  = (const float*)d_in[11];
  const float* fc2_b  = (const float*)d_in[12];
  float* out = (float*)d_out;

  char* ws = (char*)d_ws;
  size_t o = 0;
  auto alloc = [&](size_t bytes) { char* p = ws + o; o += bytes; return p; };
  u16* wqkv_t  = (u16*)alloc((size_t)C3 * Cc * 2);
  u16* wproj_t = (u16*)alloc((size_t)Cc * Cc * 2);
  u16* wfc1_t  = (u16*)alloc((size_t)4096 * Cc * 2);
  u16* wfc2_t  = (u16*)alloc((size_t)Cc * 4096 * 2);
  u16* h_bf    = (u16*)alloc((size_t)ROWS * Cc * 2);
  u16* y_bf    = (u16*)alloc((size_t)ROWS * Cc * 2);
  u16* qkv_raw = (u16*)alloc((size_t)ROWS * C3 * 2);
  u16* vt      = (u16*)alloc((size_t)Bb * Hh * Dd * Tt * 2);
  u16* hh      = qkv_raw; // aliases qkv_raw+vt, both dead by FC1 time

  wcast_t<<<dim3(C3 / 32, Cc / 32), 256, 0, stream>>>(attn_w, wqkv_t, Cc, C3);
  wcast_t<<<dim3(Cc / 32, Cc / 32), 256, 0, stream>>>(proj_w, wproj_t, Cc, Cc);
  wcast_t<<<dim3(4096 / 32, Cc / 32), 256, 0, stream>>>(fc1_w, wfc1_t, Cc, 4096);
  wcast_t<<<dim3(Cc / 32, 4096 / 32), 256, 0, stream>>>(fc2_w, wfc2_t, 4096, Cc);

  ln_kernel<<<ROWS, 256, 0, stream>>>(x, ln1_g, ln1_b, h_bf);
  gemm_bt<EPI_BIAS_BF16><<<dim3(ROWS / 128, C3 / 128), 256, 0, stream>>>(
      h_bf, wqkv_t, attn_b, nullptr, qkv_raw, ROWS, C3, Cc);
  build_vt<<<dim3(Tt / 64, Hh, Bb), 256, 0, stream>>>(qkv_raw, vt);
  flash_attn<<<dim3(Tt / 128, Hh, Bb), 256, 0, stream>>>(qkv_raw, vt, y_bf);
  gemm_bt<EPI_BIAS_RES_F32><<<dim3(ROWS / 128, Cc / 128), 256, 0, stream>>>(
      y_bf, wproj_t, proj_b, x, out, ROWS, Cc, Cc);
  ln_kernel<<<ROWS, 256, 0, stream>>>(out, ln2_g, ln2_b, h_bf);
  gemm_bt<EPI_BIAS_RELU_BF16><<<dim3(ROWS / 128, 4096 / 128), 256, 0, stream>>>(
      h_bf, wfc1_t, fc1_b, nullptr, hh, ROWS, 4096, Cc);
  gemm_bt<EPI_BIAS_RES_F32><<<dim3(ROWS / 128, Cc / 128), 256, 0, stream>>>(
      hh, wfc2_t, fc2_b, out, out, ROWS, Cc, 4096);
}

// Round 3
// 543.349 us; speedup vs baseline: 1.8556x; 1.0128x over previous
//
#include <hip/hip_runtime.h>
#include <cstdint>
#include <cstddef>

typedef __bf16 bf16x8 __attribute__((ext_vector_type(8)));
typedef float f32x4 __attribute__((ext_vector_type(4)));
typedef float f32x16 __attribute__((ext_vector_type(16)));
typedef unsigned short u16;

namespace {
constexpr int Bb = 4, Tt = 2048, Cc = 1024, Hh = 16, Dd = 64;
constexpr int ROWS = Bb * Tt;   // 8192
constexpr int C3 = 3 * Cc;      // 3072
constexpr float LNEPS = 1e-5f;
constexpr float SCL2 = 0.18033688011112042f; // 0.125 * log2(e)
}

__device__ __forceinline__ u16 f2bf(float f) {
  union { float f; unsigned u; } v; v.f = f;
  return (u16)((v.u + 0x7fffu + ((v.u >> 16) & 1u)) >> 16);
}
__device__ __forceinline__ u16 bfn(float f) {   // native v_cvt (RNE)
  union { __bf16 b; u16 u; } t; t.b = (__bf16)f; return t.u;
}
__device__ __forceinline__ unsigned pk2(float lo, float hi) {
  union { __bf16 b[2]; unsigned u; } t;
  t.b[0] = (__bf16)lo; t.b[1] = (__bf16)hi;
  return t.u;
}

typedef __attribute__((address_space(3))) unsigned lds_u32;
typedef __attribute__((address_space(1))) const unsigned glb_u32;
__device__ __forceinline__ void gload_lds16(const u16* g, u16* l) {
  __builtin_amdgcn_global_load_lds((glb_u32*)g, (lds_u32*)l, 16, 0, 0);
}

// ---------------- LayerNorm (fp32 in -> bf16 out) ----------------
__global__ __launch_bounds__(256) void ln_kernel(
    const float* __restrict__ x, const float* __restrict__ g,
    const float* __restrict__ b, u16* __restrict__ out)
{
  const int row = blockIdx.x;
  const int tid = threadIdx.x;
  const float4 v = reinterpret_cast<const float4*>(x + (size_t)row * Cc)[tid];
  float s  = v.x + v.y + v.z + v.w;
  float ss = v.x * v.x + v.y * v.y + v.z * v.z + v.w * v.w;
#pragma unroll
  for (int off = 32; off; off >>= 1) {
    s  += __shfl_xor(s, off);
    ss += __shfl_xor(ss, off);
  }
  __shared__ float sa[4], sb[4];
  const int w = tid >> 6;
  if ((tid & 63) == 0) { sa[w] = s; sb[w] = ss; }
  __syncthreads();
  s  = sa[0] + sa[1] + sa[2] + sa[3];
  ss = sb[0] + sb[1] + sb[2] + sb[3];
  const float mu   = s * (1.0f / Cc);
  const float var  = ss * (1.0f / Cc) - mu * mu;
  const float rstd = rsqrtf(var + LNEPS);
  const float4 gv = reinterpret_cast<const float4*>(g)[tid];
  const float4 bv = reinterpret_cast<const float4*>(b)[tid];
  ushort4 o;
  o.x = f2bf((v.x - mu) * rstd * gv.x + bv.x);
  o.y = f2bf((v.y - mu) * rstd * gv.y + bv.y);
  o.z = f2bf((v.z - mu) * rstd * gv.z + bv.z);
  o.w = f2bf((v.w - mu) * rstd * gv.w + bv.w);
  reinterpret_cast<ushort4*>(out + (size_t)row * Cc)[tid] = o;
}

// ---------------- weight transpose + cast: w[K][N] f32 -> wt[N][K] bf16 ----------------
__global__ __launch_bounds__(256) void wcast_t(
    const float* __restrict__ w, u16* __restrict__ wt, int K, int N)
{
  __shared__ float tile[32][33];
  const int n0 = blockIdx.x * 32, k0 = blockIdx.y * 32;
  const int tx = threadIdx.x & 31, ty = threadIdx.x >> 5; // 32x8
#pragma unroll
  for (int i = 0; i < 4; i++)
    tile[ty + i * 8][tx] = w[(size_t)(k0 + ty + i * 8) * N + n0 + tx];
  __syncthreads();
#pragma unroll
  for (int i = 0; i < 4; i++)
    wt[(size_t)(n0 + ty + i * 8) * K + k0 + tx] = f2bf(tile[tx][ty + i * 8]);
}

// ---------------- GEMM: C[M][N] = A[M][K] * Bt[N][K]^T, fused epilogues ----------------
enum { EPI_BIAS_BF16 = 0, EPI_BIAS_RELU_BF16 = 1, EPI_BIAS_RES_F32 = 2 };

template <int EPI>
__global__ __launch_bounds__(256, 3) void gemm_bt(
    const u16* __restrict__ A, const u16* __restrict__ Bt,
    const float* __restrict__ bias, const float* __restrict__ res,
    void* __restrict__ outp, int M, int N, int K)
{
  constexpr int BM = 128, BN = 128, BK = 64;
  __shared__ alignas(16) u16 As[BM][BK];
  __shared__ alignas(16) u16 Bs[BN][BK];
  const int tid  = threadIdx.x;
  const int lane = tid & 63;
  const int wv   = tid >> 6;
  const int wr   = wv >> 1, wc = wv & 1;
  const int lr   = lane & 15, lg = lane >> 4;
  const int bm = blockIdx.x * BM;
  const int bn = blockIdx.y * BN;

  f32x4 acc[4][4];
#pragma unroll
  for (int mi = 0; mi < 4; mi++)
#pragma unroll
    for (int nj = 0; nj < 4; nj++)
      acc[mi][nj] = (f32x4){0.f, 0.f, 0.f, 0.f};

  const int srow = tid >> 3;          // 0..31
  const int scol = (tid & 7) * 8;     // 0,8,..,56 (elems)
  const u16* ga = &A [(size_t)(bm + srow) * K + scol];
  const u16* gb = &Bt[(size_t)(bn + srow) * K + scol];
  u16* as_dst = &As[0][0] + (size_t)tid * 8;
  u16* bs_dst = &Bs[0][0] + (size_t)tid * 8;

  for (int k0 = 0; k0 < K; k0 += BK) {
#pragma unroll
    for (int p = 0; p < 4; p++) {
      gload_lds16(ga + (size_t)p * 32 * K + k0, as_dst + p * 2048);
      gload_lds16(gb + (size_t)p * 32 * K + k0, bs_dst + p * 2048);
    }
    __syncthreads();
#pragma unroll
    for (int kk = 0; kk < BK; kk += 32) {
      bf16x8 af[4], bfr[4];
#pragma unroll
      for (int mi = 0; mi < 4; mi++)
        af[mi] = *reinterpret_cast<const bf16x8*>(&As[wr * 64 + mi * 16 + lr][kk + lg * 8]);
#pragma unroll
      for (int nj = 0; nj < 4; nj++)
        bfr[nj] = *reinterpret_cast<const bf16x8*>(&Bs[wc * 64 + nj * 16 + lr][kk + lg * 8]);
#pragma unroll
      for (int mi = 0; mi < 4; mi++)
#pragma unroll
        for (int nj = 0; nj < 4; nj++)
          acc[mi][nj] = __builtin_amdgcn_mfma_f32_16x16x32_bf16(af[mi], bfr[nj], acc[mi][nj], 0, 0, 0);
    }
    __syncthreads();
  }

#pragma unroll
  for (int mi = 0; mi < 4; mi++) {
#pragma unroll
    for (int nj = 0; nj < 4; nj++) {
      const int col = bn + wc * 64 + nj * 16 + lr;
      const float bv = bias[col];
#pragma unroll
      for (int r = 0; r < 4; r++) {
        const int row = bm + wr * 64 + mi * 16 + lg * 4 + r;
        float v = acc[mi][nj][r] + bv;
        if constexpr (EPI == EPI_BIAS_RELU_BF16) v = fmaxf(v, 0.0f);
        if constexpr (EPI == EPI_BIAS_RES_F32) {
          float* out = (float*)outp;
          out[(size_t)row * N + col] = v + res[(size_t)row * N + col];
        } else {
          ((u16*)outp)[(size_t)row * N + col] = f2bf(v);
        }
      }
    }
  }
}

// ---------------- V transpose: qkv[B][T][3C] (v part) -> vt[B][H][D][T] ----------------
__global__ __launch_bounds__(256) void build_vt(
    const u16* __restrict__ qkv, u16* __restrict__ vt)
{
  __shared__ u16 tile[64][80];
  const int t0 = blockIdx.x * 64;
  const int h  = blockIdx.y;
  const int b  = blockIdx.z;
  const int tid = threadIdx.x;
  const int rr = tid >> 3, cc = (tid & 7) * 8;
#pragma unroll
  for (int p = 0; p < 2; p++) {
    const int t = rr + p * 32;
    bf16x8 v = *reinterpret_cast<const bf16x8*>(
        &qkv[(size_t)(b * Tt + t0 + t) * C3 + 2 * Cc + h * Dd + cc]);
    *reinterpret_cast<bf16x8*>(&tile[t][cc]) = v;
  }
  __syncthreads();
#pragma unroll
  for (int p = 0; p < 2; p++) {
    const int d = rr + p * 32;
    union { u16 u[8]; int4 v; } o;
#pragma unroll
    for (int j = 0; j < 8; j++) o.u[j] = tile[cc + j][d];
    *reinterpret_cast<int4*>(&vt[(size_t)((b * Hh + h) * Dd + d) * Tt + t0 + cc]) = o.v;
  }
}

// ---------------- flash attention: 32x32 double-swapped, no LDS ----------------
// Wave owns 32 q-rows. QK^T: mfma(K,Q) -> S[key][q], q = lane&31 (softmax
// state lane-local). PV: mfma(V^T, P^T) -> O[d][q], q = lane&31 (rescale &
// normalize lane-local, zero shuffles). P^T B-frags built in-register via
// cvt_pk + half-swap. Defer-max (T13, e^8). XCD-bijective block swizzle pins
// each (b,h)'s K/V (512 KB) to one XCD L2; longest tiles dispatch first.
__global__ __launch_bounds__(256, 3) void flash_attn(
    const u16* __restrict__ qkv,   // [B][T][3C]
    const u16* __restrict__ vt,    // [B][H][D][T]
    u16* __restrict__ y)           // [B][T][C]
{
  const int tid = threadIdx.x, lane = tid & 63, wv = tid >> 6;
  const int l31 = lane & 31, hf = lane >> 5;
  const bool lo = (lane < 32);

  // XCD swizzle: 1024 blocks = 8 XCDs x 128; logical l = xcd*128 + slot
  const int bhw = blockIdx.x;
  const int l = (bhw & 7) * 128 + (bhw >> 3);
  const int bh = l >> 4, bx = l & 15;
  const int b = bh >> 4, h = bh & 15;
  const int t = (15 - bx) * 4 + wv;     // q-tile 0..63, longest first
  const int q0 = t * 32;

  const u16* qbase = qkv + (size_t)b * Tt * C3 + h * Dd;
  const u16* kbase = qbase + Cc;
  const u16* vbase = vt + (size_t)bh * Dd * Tt;

  // Q B-frags: B[k=d][n=q]: q = l31, d = kc*16 + hf*8 + j
  bf16x8 qf[4];
#pragma unroll
  for (int kc = 0; kc < 4; kc++)
    qf[kc] = *reinterpret_cast<const bf16x8*>(
        &qbase[(size_t)(q0 + l31) * C3 + kc * 16 + hf * 8]);

  f32x16 oacc[2];
#pragma unroll
  for (int i = 0; i < 16; i++) { oacc[0][i] = 0.f; oacc[1][i] = 0.f; }
  float mrun = -INFINITY, lpart = 0.0f;

  // K A-frags: A[m=key][k=d]: key = l31, d = kc*16 + hf*8 + j
  bf16x8 kf[4];
#pragma unroll
  for (int kc = 0; kc < 4; kc++)
    kf[kc] = *reinterpret_cast<const bf16x8*>(
        &kbase[(size_t)l31 * C3 + kc * 16 + hf * 8]);

  for (int k0 = 0; k0 <= q0; k0 += 32) {
    // V A-frags: A[m=d][k=key]: d = d0i*32 + l31, key = ch*16 + hf*8 + j
    bf16x8 vf[2][2];
#pragma unroll
    for (int d0i = 0; d0i < 2; d0i++)
#pragma unroll
      for (int ch = 0; ch < 2; ch++)
        vf[d0i][ch] = *reinterpret_cast<const bf16x8*>(
            &vbase[(size_t)(d0i * 32 + l31) * Tt + k0 + ch * 16 + hf * 8]);

    f32x16 sacc;
#pragma unroll
    for (int i = 0; i < 16; i++) sacc[i] = 0.f;
#pragma unroll
    for (int kc = 0; kc < 4; kc++)
      sacc = __builtin_amdgcn_mfma_f32_32x32x16_bf16(kf[kc], qf[kc], sacc, 0, 0, 0);

    // prefetch next K tile
    bf16x8 kn[4];
    if (k0 < q0) {
#pragma unroll
      for (int kc = 0; kc < 4; kc++)
        kn[kc] = *reinterpret_cast<const bf16x8*>(
            &kbase[(size_t)(k0 + 32 + l31) * C3 + kc * 16 + hf * 8]);
    }

    float sv[16];
#pragma unroll
    for (int r = 0; r < 16; r++) sv[r] = sacc[r];
    if (k0 == q0) {   // diagonal tile: mask key > q (key = (r&3)+8*(r>>2)+4hf)
#pragma unroll
      for (int r = 0; r < 16; r++)
        if ((r & 3) + 8 * (r >> 2) + 4 * hf > l31) sv[r] = -INFINITY;
    }

    // row max: 15 in-lane + cross-half
    float m8 = sv[0];
#pragma unroll
    for (int r = 1; r < 16; r++) m8 = fmaxf(m8, sv[r]);
    m8 = fmaxf(m8, __shfl_xor(m8, 32));

    if (!__all(m8 - mrun <= 64.0f)) {   // defer-max: 64 raw = 8 nats
      const float mnew  = fmaxf(mrun, m8);
      const float alpha = exp2f((mrun - mnew) * SCL2);
      lpart *= alpha;
#pragma unroll
      for (int i = 0; i < 16; i++) { oacc[0][i] *= alpha; oacc[1][i] *= alpha; }
      mrun = mnew;
    }

    const float ms = mrun * SCL2;
    float p[16]; float psum = 0.0f;
#pragma unroll
    for (int r = 0; r < 16; r++) {
      p[r] = exp2f(sv[r] * SCL2 - ms);
      psum += p[r];
    }
    lpart += psum;

    // P^T B-frags: B[k=key][n=q]: lane needs keys hf*8+j (chunk base 16*ch)
    unsigned pw[2][4];
#pragma unroll
    for (int ch = 0; ch < 2; ch++) {
      const int bs = ch * 8;
      unsigned w0 = pk2(p[bs + 0], p[bs + 1]);
      unsigned w2 = pk2(p[bs + 4], p[bs + 5]);
      unsigned h0 = __shfl_xor((int)w0, 32), h2 = __shfl_xor((int)w2, 32);
      pw[ch][0] = lo ? w0 : h2;
      pw[ch][2] = lo ? h0 : w2;
      unsigned w1 = pk2(p[bs + 2], p[bs + 3]);
      unsigned w3 = pk2(p[bs + 6], p[bs + 7]);
      unsigned h1 = __shfl_xor((int)w1, 32), h3 = __shfl_xor((int)w3, 32);
      pw[ch][1] = lo ? w1 : h3;
      pw[ch][3] = lo ? h1 : w3;
    }

#pragma unroll
    for (int d0i = 0; d0i < 2; d0i++)
#pragma unroll
      for (int ch = 0; ch < 2; ch++) {
        union { unsigned w[4]; bf16x8 v; } pb;
        pb.w[0] = pw[ch][0]; pb.w[1] = pw[ch][1];
        pb.w[2] = pw[ch][2]; pb.w[3] = pw[ch][3];
        oacc[d0i] = __builtin_amdgcn_mfma_f32_32x32x16_bf16(vf[d0i][ch], pb.v, oacc[d0i], 0, 0, 0);
      }

    if (k0 < q0) {
#pragma unroll
      for (int kc = 0; kc < 4; kc++) kf[kc] = kn[kc];
    }
  }

  // finish: lsum across halves (same q), normalize, store O[d][q]
  const float ls = lpart + __shfl_xor(lpart, 32);
  const float inv = 1.0f / ls;
  u16* yrow = y + (size_t)(b * Tt + q0 + l31) * Cc + h * Dd;
#pragma unroll
  for (int d0i = 0; d0i < 2; d0i++)
#pragma unroll
    for (int qd = 0; qd < 4; qd++) {
      ushort4 o;
      o.x = bfn(oacc[d0i][qd * 4 + 0] * inv);
      o.y = bfn(oacc[d0i][qd * 4 + 1] * inv);
      o.z = bfn(oacc[d0i][qd * 4 + 2] * inv);
      o.w = bfn(oacc[d0i][qd * 4 + 3] * inv);
      *reinterpret_cast<ushort4*>(&yrow[d0i * 32 + qd * 8 + hf * 4]) = o;
    }
}

// ---------------- launch ----------------
extern "C" void kernel_launch(void* const* d_in, const int* in_sizes, int n_in,
                              void* d_out, int out_size, void* d_ws, size_t ws_size,
                              hipStream_t stream)
{
  const float* x      = (const float*)d_in[0];
  const float* ln1_g  = (const float*)d_in[1];
  const float* ln1_b  = (const float*)d_in[2];
  const float* attn_w = (const float*)d_in[3];
  const float* attn_b = (const float*)d_in[4];
  const float* proj_w = (const float*)d_in[5];
  const float* proj_b = (const float*)d_in[6];
  const float* ln2_g  = (const float*)d_in[7];
  const float* ln2_b  = (const float*)d_in[8];
  const float* fc1_w  = (const float*)d_in[9];
  const float* fc1_b  = (const float*)d_in[10];
  const float* fc2_w  = (const float*)d_in[11];
  const float* fc2_b  = (const float*)d_in[12];
  float* out = (float*)d_out;

  char* ws = (char*)d_ws;
  size_t o = 0;
  auto alloc = [&](size_t bytes) { char* p = ws + o; o += bytes; return p; };
  u16* wqkv_t  = (u16*)alloc((size_t)C3 * Cc * 2);
  u16* wproj_t = (u16*)alloc((size_t)Cc * Cc * 2);
  u16* wfc1_t  = (u16*)alloc((size_t)4096 * Cc * 2);
  u16* wfc2_t  = (u16*)alloc((size_t)Cc * 4096 * 2);
  u16* h_bf    = (u16*)alloc((size_t)ROWS * Cc * 2);
  u16* y_bf    = (u16*)alloc((size_t)ROWS * Cc * 2);
  u16* qkv_raw = (u16*)alloc((size_t)ROWS * C3 * 2);
  u16* vt      = (u16*)alloc((size_t)Bb * Hh * Dd * Tt * 2);
  u16* hh      = qkv_raw; // aliases qkv_raw+vt, both dead by FC1 time

  wcast_t<<<dim3(C3 / 32, Cc / 32), 256, 0, stream>>>(attn_w, wqkv_t, Cc, C3);
  wcast_t<<<dim3(Cc / 32, Cc / 32), 256, 0, stream>>>(proj_w, wproj_t, Cc, Cc);
  wcast_t<<<dim3(4096 / 32, Cc / 32), 256, 0, stream>>>(fc1_w, wfc1_t, Cc, 4096);
  wcast_t<<<dim3(Cc / 32, 4096 / 32), 256, 0, stream>>>(fc2_w, wfc2_t, 4096, Cc);

  ln_kernel<<<ROWS, 256, 0, stream>>>(x, ln1_g, ln1_b, h_bf);
  gemm_bt<EPI_BIAS_BF16><<<dim3(ROWS / 128, C3 / 128), 256, 0, stream>>>(
      h_bf, wqkv_t, attn_b, nullptr, qkv_raw, ROWS, C3, Cc);
  build_vt<<<dim3(Tt / 64, Hh, Bb), 256, 0, stream>>>(qkv_raw, vt);
  flash_attn<<<dim3(1024), 256, 0, stream>>>(qkv_raw, vt, y_bf);
  gemm_bt<EPI_BIAS_RES_F32><<<dim3(ROWS / 128, Cc / 128), 256, 0, stream>>>(
      y_bf, wproj_t, proj_b, x, out, ROWS, Cc, Cc);
  ln_kernel<<<ROWS, 256, 0, stream>>>(out, ln2_g, ln2_b, h_bf);
  gemm_bt<EPI_BIAS_RELU_BF16><<<dim3(ROWS / 128, 4096 / 128), 256, 0, stream>>>(
      h_bf, wfc1_t, fc1_b, nullptr, hh, ROWS, 4096, Cc);
  gemm_bt<EPI_BIAS_RES_F32><<<dim3(ROWS / 128, Cc / 128), 256, 0, stream>>>(
      hh, wfc2_t, fc2_b, out, out, ROWS, Cc, 4096);
}

// Round 4
// 455.846 us; speedup vs baseline: 2.2118x; 1.1920x over previous
//
#include <hip/hip_runtime.h>
#include <cstdint>
#include <cstddef>

typedef __bf16 bf16x8 __attribute__((ext_vector_type(8)));
typedef float f32x4 __attribute__((ext_vector_type(4)));
typedef float f32x16 __attribute__((ext_vector_type(16)));
typedef unsigned short u16;

namespace {
constexpr int Bb = 4, Tt = 2048, Cc = 1024, Hh = 16, Dd = 64;
constexpr int ROWS = Bb * Tt;   // 8192
constexpr int C3 = 3 * Cc;      // 3072
constexpr float LNEPS = 1e-5f;
constexpr float SCL2 = 0.18033688011112042f; // 0.125 * log2(e)
}

__device__ __forceinline__ u16 f2bf(float f) {
  union { float f; unsigned u; } v; v.f = f;
  return (u16)((v.u + 0x7fffu + ((v.u >> 16) & 1u)) >> 16);
}
__device__ __forceinline__ u16 bfn(float f) {   // native v_cvt (RNE)
  union { __bf16 b; u16 u; } t; t.b = (__bf16)f; return t.u;
}
__device__ __forceinline__ unsigned pk2(float lo, float hi) {
  union { __bf16 b[2]; unsigned u; } t;
  t.b[0] = (__bf16)lo; t.b[1] = (__bf16)hi;
  return t.u;
}
__device__ __forceinline__ float exp2_hw(float x) {  // 2^x, one v_exp_f32
  float r;
  asm("v_exp_f32 %0, %1" : "=v"(r) : "v"(x));
  return r;
}

typedef __attribute__((address_space(3))) unsigned lds_u32;
typedef __attribute__((address_space(1))) const unsigned glb_u32;
__device__ __forceinline__ void gload_lds16(const u16* g, u16* l) {
  __builtin_amdgcn_global_load_lds((glb_u32*)g, (lds_u32*)l, 16, 0, 0);
}

// ---------------- LayerNorm (fp32 in -> bf16 out) ----------------
__global__ __launch_bounds__(256) void ln_kernel(
    const float* __restrict__ x, const float* __restrict__ g,
    const float* __restrict__ b, u16* __restrict__ out)
{
  const int row = blockIdx.x;
  const int tid = threadIdx.x;
  const float4 v = reinterpret_cast<const float4*>(x + (size_t)row * Cc)[tid];
  float s  = v.x + v.y + v.z + v.w;
  float ss = v.x * v.x + v.y * v.y + v.z * v.z + v.w * v.w;
#pragma unroll
  for (int off = 32; off; off >>= 1) {
    s  += __shfl_xor(s, off);
    ss += __shfl_xor(ss, off);
  }
  __shared__ float sa[4], sb[4];
  const int w = tid >> 6;
  if ((tid & 63) == 0) { sa[w] = s; sb[w] = ss; }
  __syncthreads();
  s  = sa[0] + sa[1] + sa[2] + sa[3];
  ss = sb[0] + sb[1] + sb[2] + sb[3];
  const float mu   = s * (1.0f / Cc);
  const float var  = ss * (1.0f / Cc) - mu * mu;
  const float rstd = rsqrtf(var + LNEPS);
  const float4 gv = reinterpret_cast<const float4*>(g)[tid];
  const float4 bv = reinterpret_cast<const float4*>(b)[tid];
  ushort4 o;
  o.x = f2bf((v.x - mu) * rstd * gv.x + bv.x);
  o.y = f2bf((v.y - mu) * rstd * gv.y + bv.y);
  o.z = f2bf((v.z - mu) * rstd * gv.z + bv.z);
  o.w = f2bf((v.w - mu) * rstd * gv.w + bv.w);
  reinterpret_cast<ushort4*>(out + (size_t)row * Cc)[tid] = o;
}

// ---------------- weight transpose + cast: w[K][N] f32 -> wt[N][K] bf16 ----------------
__global__ __launch_bounds__(256) void wcast_t(
    const float* __restrict__ w, u16* __restrict__ wt, int K, int N)
{
  __shared__ float tile[32][33];
  const int n0 = blockIdx.x * 32, k0 = blockIdx.y * 32;
  const int tx = threadIdx.x & 31, ty = threadIdx.x >> 5; // 32x8
#pragma unroll
  for (int i = 0; i < 4; i++)
    tile[ty + i * 8][tx] = w[(size_t)(k0 + ty + i * 8) * N + n0 + tx];
  __syncthreads();
#pragma unroll
  for (int i = 0; i < 4; i++)
    wt[(size_t)(n0 + ty + i * 8) * K + k0 + tx] = f2bf(tile[tx][ty + i * 8]);
}

// ---------------- GEMM: C[M][N] = A[M][K] * Bt[N][K]^T, fused epilogues ----------------
// m97 structure + T1 XCD-bijective swizzle (bm-fastest within XCD chunk:
// B-panel stays L2-resident per XCD while A streams via L3). M == 8192 fixed.
enum { EPI_BIAS_BF16 = 0, EPI_BIAS_RELU_BF16 = 1, EPI_BIAS_RES_F32 = 2 };

template <int EPI>
__global__ __launch_bounds__(256, 3) void gemm_bt(
    const u16* __restrict__ A, const u16* __restrict__ Bt,
    const float* __restrict__ bias, const float* __restrict__ res,
    void* __restrict__ outp, int M, int N, int K)
{
  constexpr int BM = 128, BN = 128, BK = 64;
  __shared__ alignas(16) u16 As[BM][BK];
  __shared__ alignas(16) u16 Bs[BN][BK];
  const int tid  = threadIdx.x;
  const int lane = tid & 63;
  const int wv   = tid >> 6;
  const int wr   = wv >> 1, wc = wv & 1;
  const int lr   = lane & 15, lg = lane >> 4;

  // XCD swizzle: grid %8 == 0 guaranteed; lid = xcd*chunk + slot
  const int q8  = (int)gridDim.x >> 3;
  const int lid = ((int)blockIdx.x & 7) * q8 + ((int)blockIdx.x >> 3);
  const int bm = (lid & 63) << 7;     // M/128 == 64, bm-fastest
  const int bn = (lid >> 6) << 7;

  f32x4 acc[4][4];
#pragma unroll
  for (int mi = 0; mi < 4; mi++)
#pragma unroll
    for (int nj = 0; nj < 4; nj++)
      acc[mi][nj] = (f32x4){0.f, 0.f, 0.f, 0.f};

  const int srow = tid >> 3;          // 0..31
  const int scol = (tid & 7) * 8;     // 0,8,..,56 (elems)
  const u16* ga = &A [(size_t)(bm + srow) * K + scol];
  const u16* gb = &Bt[(size_t)(bn + srow) * K + scol];
  u16* as_dst = &As[0][0] + (size_t)tid * 8;
  u16* bs_dst = &Bs[0][0] + (size_t)tid * 8;

  for (int k0 = 0; k0 < K; k0 += BK) {
#pragma unroll
    for (int p = 0; p < 4; p++) {
      gload_lds16(ga + (size_t)p * 32 * K + k0, as_dst + p * 2048);
      gload_lds16(gb + (size_t)p * 32 * K + k0, bs_dst + p * 2048);
    }
    __syncthreads();
#pragma unroll
    for (int kk = 0; kk < BK; kk += 32) {
      bf16x8 af[4], bfr[4];
#pragma unroll
      for (int mi = 0; mi < 4; mi++)
        af[mi] = *reinterpret_cast<const bf16x8*>(&As[wr * 64 + mi * 16 + lr][kk + lg * 8]);
#pragma unroll
      for (int nj = 0; nj < 4; nj++)
        bfr[nj] = *reinterpret_cast<const bf16x8*>(&Bs[wc * 64 + nj * 16 + lr][kk + lg * 8]);
#pragma unroll
      for (int mi = 0; mi < 4; mi++)
#pragma unroll
        for (int nj = 0; nj < 4; nj++)
          acc[mi][nj] = __builtin_amdgcn_mfma_f32_16x16x32_bf16(af[mi], bfr[nj], acc[mi][nj], 0, 0, 0);
    }
    __syncthreads();
  }

#pragma unroll
  for (int mi = 0; mi < 4; mi++) {
#pragma unroll
    for (int nj = 0; nj < 4; nj++) {
      const int col = bn + wc * 64 + nj * 16 + lr;
      const float bv = bias[col];
#pragma unroll
      for (int r = 0; r < 4; r++) {
        const int row = bm + wr * 64 + mi * 16 + lg * 4 + r;
        float v = acc[mi][nj][r] + bv;
        if constexpr (EPI == EPI_BIAS_RELU_BF16) v = fmaxf(v, 0.0f);
        if constexpr (EPI == EPI_BIAS_RES_F32) {
          float* out = (float*)outp;
          out[(size_t)row * N + col] = v + res[(size_t)row * N + col];
        } else {
          ((u16*)outp)[(size_t)row * N + col] = f2bf(v);
        }
      }
    }
  }
}

// ---------------- V transpose: qkv[B][T][3C] (v part) -> vt[B][H][D][T] ----------------
__global__ __launch_bounds__(256) void build_vt(
    const u16* __restrict__ qkv, u16* __restrict__ vt)
{
  __shared__ u16 tile[64][80];
  const int t0 = blockIdx.x * 64;
  const int h  = blockIdx.y;
  const int b  = blockIdx.z;
  const int tid = threadIdx.x;
  const int rr = tid >> 3, cc = (tid & 7) * 8;
#pragma unroll
  for (int p = 0; p < 2; p++) {
    const int t = rr + p * 32;
    bf16x8 v = *reinterpret_cast<const bf16x8*>(
        &qkv[(size_t)(b * Tt + t0 + t) * C3 + 2 * Cc + h * Dd + cc]);
    *reinterpret_cast<bf16x8*>(&tile[t][cc]) = v;
  }
  __syncthreads();
#pragma unroll
  for (int p = 0; p < 2; p++) {
    const int d = rr + p * 32;
    union { u16 u[8]; int4 v; } o;
#pragma unroll
    for (int j = 0; j < 8; j++) o.u[j] = tile[cc + j][d];
    *reinterpret_cast<int4*>(&vt[(size_t)((b * Hh + h) * Dd + d) * Tt + t0 + cc]) = o.v;
  }
}

// ---------------- flash attention: 32x32 double-swapped, pair-balanced ----------------
// Each wave processes the q-tile PAIR (pi, 63-pi): exactly 65 iterations per
// wave -> every block has identical duration (no scheduler assumptions).
// QK^T: mfma(K,Q) -> S[key][q], q = lane&31. PV: mfma(V^T,P^T) -> O[d][q].
// Softmax state fully lane-local; defer-max (T13); XCD swizzle: 8 bh per XCD.
__global__ __launch_bounds__(256, 4) void flash_attn(
    const u16* __restrict__ qkv,   // [B][T][3C]
    const u16* __restrict__ vt,    // [B][H][D][T]
    u16* __restrict__ y)           // [B][T][C]
{
  const int tid = threadIdx.x, lane = tid & 63, wv = tid >> 6;
  const int l31 = lane & 31, hf = lane >> 5;
  const bool lo = (lane < 32);

  // 512 blocks = 8 XCDs x 64; lid = bh*8 + pg (bh pinned to one XCD)
  const int bid = blockIdx.x;
  const int lid = (bid & 7) * 64 + (bid >> 3);
  const int bh = lid >> 3, pg = lid & 7;
  const int b = bh >> 4, h = bh & 15;
  const int pi = pg * 4 + wv;        // 0..31 -> tiles {pi, 63-pi}

  const u16* qbase = qkv + (size_t)b * Tt * C3 + h * Dd;
  const u16* kbase = qbase + Cc;
  const u16* vbase = vt + (size_t)bh * Dd * Tt;

#pragma unroll
  for (int ti = 0; ti < 2; ti++) {
    const int t = ti ? (63 - pi) : pi;
    const int q0 = t * 32;

    // Q B-frags: B[k=d][n=q]: q = l31, d = kc*16 + hf*8 + j
    bf16x8 qf[4];
#pragma unroll
    for (int kc = 0; kc < 4; kc++)
      qf[kc] = *reinterpret_cast<const bf16x8*>(
          &qbase[(size_t)(q0 + l31) * C3 + kc * 16 + hf * 8]);

    f32x16 oacc[2];
#pragma unroll
    for (int i = 0; i < 16; i++) { oacc[0][i] = 0.f; oacc[1][i] = 0.f; }
    float mrun = -INFINITY, lpart = 0.0f;

    // K A-frags: A[m=key][k=d]: key = l31, d = kc*16 + hf*8 + j
    const u16* kptr = &kbase[(size_t)l31 * C3 + hf * 8];
    const u16* vptr0 = &vbase[(size_t)l31 * Tt + hf * 8];
    const u16* vptr1 = vptr0 + (size_t)32 * Tt;
    bf16x8 kf[4];
#pragma unroll
    for (int kc = 0; kc < 4; kc++)
      kf[kc] = *reinterpret_cast<const bf16x8*>(kptr + kc * 16);

    for (int k0 = 0; k0 <= q0; k0 += 32) {
      // V A-frags: A[m=d][k=key]: d = d0i*32 + l31, key = ch*16 + hf*8 + j
      bf16x8 vf[2][2];
#pragma unroll
      for (int ch = 0; ch < 2; ch++) {
        vf[0][ch] = *reinterpret_cast<const bf16x8*>(vptr0 + ch * 16);
        vf[1][ch] = *reinterpret_cast<const bf16x8*>(vptr1 + ch * 16);
      }
      vptr0 += 32; vptr1 += 32;

      f32x16 sacc;
#pragma unroll
      for (int i = 0; i < 16; i++) sacc[i] = 0.f;
#pragma unroll
      for (int kc = 0; kc < 4; kc++)
        sacc = __builtin_amdgcn_mfma_f32_32x32x16_bf16(kf[kc], qf[kc], sacc, 0, 0, 0);

      // prefetch next K tile
      kptr += (size_t)32 * C3;
      bf16x8 kn[4];
      if (k0 < q0) {
#pragma unroll
        for (int kc = 0; kc < 4; kc++)
          kn[kc] = *reinterpret_cast<const bf16x8*>(kptr + kc * 16);
      }

      float sv[16];
#pragma unroll
      for (int r = 0; r < 16; r++) sv[r] = sacc[r];
      if (k0 == q0) {   // diagonal: mask key > q (key = (r&3)+8*(r>>2)+4hf)
#pragma unroll
        for (int r = 0; r < 16; r++)
          if ((r & 3) + 8 * (r >> 2) + 4 * hf > l31) sv[r] = -INFINITY;
      }

      // row max: max3-friendly tree (depth ~4) + cross-half
      float ma = fmaxf(fmaxf(sv[0], sv[1]), fmaxf(sv[2], sv[3]));
      float mb = fmaxf(fmaxf(sv[4], sv[5]), fmaxf(sv[6], sv[7]));
      float mc = fmaxf(fmaxf(sv[8], sv[9]), fmaxf(sv[10], sv[11]));
      float md = fmaxf(fmaxf(sv[12], sv[13]), fmaxf(sv[14], sv[15]));
      float m8 = fmaxf(fmaxf(ma, mb), fmaxf(mc, md));
      m8 = fmaxf(m8, __shfl_xor(m8, 32));

      if (!__all(m8 - mrun <= 64.0f)) {   // defer-max: 64 raw = 8 nats
        const float mnew  = fmaxf(mrun, m8);
        const float alpha = exp2_hw((mrun - mnew) * SCL2);
        lpart *= alpha;
#pragma unroll
        for (int i = 0; i < 16; i++) { oacc[0][i] *= alpha; oacc[1][i] *= alpha; }
        mrun = mnew;
      }

      const float ms = mrun * SCL2;
      float p[16];
#pragma unroll
      for (int r = 0; r < 16; r++)
        p[r] = exp2_hw(fmaf(sv[r], SCL2, -ms));
      // tree-sum (depth 4; fp adds don't reassociate on their own)
      {
        float s0 = (p[0] + p[1]) + (p[2] + p[3]);
        float s1 = (p[4] + p[5]) + (p[6] + p[7]);
        float s2 = (p[8] + p[9]) + (p[10] + p[11]);
        float s3 = (p[12] + p[13]) + (p[14] + p[15]);
        lpart += (s0 + s1) + (s2 + s3);
      }

      // P^T B-frags: B[k=key][n=q]: lane needs keys hf*8+j (chunk base 16*ch)
      unsigned pw[2][4];
#pragma unroll
      for (int ch = 0; ch < 2; ch++) {
        const int bs = ch * 8;
        unsigned w0 = pk2(p[bs + 0], p[bs + 1]);
        unsigned w2 = pk2(p[bs + 4], p[bs + 5]);
        unsigned h0 = __shfl_xor((int)w0, 32), h2 = __shfl_xor((int)w2, 32);
        pw[ch][0] = lo ? w0 : h2;
        pw[ch][2] = lo ? h0 : w2;
        unsigned w1 = pk2(p[bs + 2], p[bs + 3]);
        unsigned w3 = pk2(p[bs + 6], p[bs + 7]);
        unsigned h1 = __shfl_xor((int)w1, 32), h3 = __shfl_xor((int)w3, 32);
        pw[ch][1] = lo ? w1 : h3;
        pw[ch][3] = lo ? h1 : w3;
      }

#pragma unroll
      for (int d0i = 0; d0i < 2; d0i++)
#pragma unroll
        for (int ch = 0; ch < 2; ch++) {
          union { unsigned w[4]; bf16x8 v; } pb;
          pb.w[0] = pw[ch][0]; pb.w[1] = pw[ch][1];
          pb.w[2] = pw[ch][2]; pb.w[3] = pw[ch][3];
          oacc[d0i] = __builtin_amdgcn_mfma_f32_32x32x16_bf16(vf[d0i][ch], pb.v, oacc[d0i], 0, 0, 0);
        }

      if (k0 < q0) {
#pragma unroll
        for (int kc = 0; kc < 4; kc++) kf[kc] = kn[kc];
      }
    }

    // finish: lsum across halves (same q), normalize, store O[d][q]
    const float ls = lpart + __shfl_xor(lpart, 32);
    const float inv = 1.0f / ls;
    u16* yrow = y + (size_t)(b * Tt + q0 + l31) * Cc + h * Dd;
#pragma unroll
    for (int d0i = 0; d0i < 2; d0i++)
#pragma unroll
      for (int qd = 0; qd < 4; qd++) {
        ushort4 o;
        o.x = bfn(oacc[d0i][qd * 4 + 0] * inv);
        o.y = bfn(oacc[d0i][qd * 4 + 1] * inv);
        o.z = bfn(oacc[d0i][qd * 4 + 2] * inv);
        o.w = bfn(oacc[d0i][qd * 4 + 3] * inv);
        *reinterpret_cast<ushort4*>(&yrow[d0i * 32 + qd * 8 + hf * 4]) = o;
      }
  }
}

// ---------------- launch ----------------
extern "C" void kernel_launch(void* const* d_in, const int* in_sizes, int n_in,
                              void* d_out, int out_size, void* d_ws, size_t ws_size,
                              hipStream_t stream)
{
  const float* x      = (const float*)d_in[0];
  const float* ln1_g  = (const float*)d_in[1];
  const float* ln1_b  = (const float*)d_in[2];
  const float* attn_w = (const float*)d_in[3];
  const float* attn_b = (const float*)d_in[4];
  const float* proj_w = (const float*)d_in[5];
  const float* proj_b = (const float*)d_in[6];
  const float* ln2_g  = (const float*)d_in[7];
  const float* ln2_b  = (const float*)d_in[8];
  const float* fc1_w  = (const float*)d_in[9];
  const float* fc1_b  = (const float*)d_in[10];
  const float* fc2_w  = (const float*)d_in[11];
  const float* fc2_b  = (const float*)d_in[12];
  float* out = (float*)d_out;

  char* ws = (char*)d_ws;
  size_t o = 0;
  auto alloc = [&](size_t bytes) { char* p = ws + o; o += bytes; return p; };
  u16* wqkv_t  = (u16*)alloc((size_t)C3 * Cc * 2);
  u16* wproj_t = (u16*)alloc((size_t)Cc * Cc * 2);
  u16* wfc1_t  = (u16*)alloc((size_t)4096 * Cc * 2);
  u16* wfc2_t  = (u16*)alloc((size_t)Cc * 4096 * 2);
  u16* h_bf    = (u16*)alloc((size_t)ROWS * Cc * 2);
  u16* y_bf    = (u16*)alloc((size_t)ROWS * Cc * 2);
  u16* qkv_raw = (u16*)alloc((size_t)ROWS * C3 * 2);
  u16* vt      = (u16*)alloc((size_t)Bb * Hh * Dd * Tt * 2);
  u16* hh      = qkv_raw; // aliases qkv_raw+vt, both dead by FC1 time

  wcast_t<<<dim3(C3 / 32, Cc / 32), 256, 0, stream>>>(attn_w, wqkv_t, Cc, C3);
  wcast_t<<<dim3(Cc / 32, Cc / 32), 256, 0, stream>>>(proj_w, wproj_t, Cc, Cc);
  wcast_t<<<dim3(4096 / 32, Cc / 32), 256, 0, stream>>>(fc1_w, wfc1_t, Cc, 4096);
  wcast_t<<<dim3(Cc / 32, 4096 / 32), 256, 0, stream>>>(fc2_w, wfc2_t, 4096, Cc);

  ln_kernel<<<ROWS, 256, 0, stream>>>(x, ln1_g, ln1_b, h_bf);
  gemm_bt<EPI_BIAS_BF16><<<64 * (C3 / 128), 256, 0, stream>>>(
      h_bf, wqkv_t, attn_b, nullptr, qkv_raw, ROWS, C3, Cc);
  build_vt<<<dim3(Tt / 64, Hh, Bb), 256, 0, stream>>>(qkv_raw, vt);
  flash_attn<<<dim3(512), 256, 0, stream>>>(qkv_raw, vt, y_bf);
  gemm_bt<EPI_BIAS_RES_F32><<<64 * (Cc / 128), 256, 0, stream>>>(
      y_bf, wproj_t, proj_b, x, out, ROWS, Cc, Cc);
  ln_kernel<<<ROWS, 256, 0, stream>>>(out, ln2_g, ln2_b, h_bf);
  gemm_bt<EPI_BIAS_RELU_BF16><<<64 * (4096 / 128), 256, 0, stream>>>(
      h_bf, wfc1_t, fc1_b, nullptr, hh, ROWS, 4096, Cc);
  gemm_bt<EPI_BIAS_RES_F32><<<64 * (Cc / 128), 256, 0, stream>>>(
      hh, wfc2_t, fc2_b, out, out, ROWS, Cc, 4096);
}